// Round 13
// baseline (48.870 us; speedup 1.0000x reference)
//
#include <hip/hip_runtime.h>
#include <hip/hip_bf16.h>
#include <cstdint>
#include <cstddef>

#define KSZ 5
#define KK 25
#define EMB 64
#define CC 128
#define FILTERS 128
#define CST 32   // padded conv-out stride (f_conv/c_conv rows, 128B aligned)

typedef __attribute__((ext_vector_type(8))) short short8;
typedef __attribute__((ext_vector_type(4))) float floatx4;

__device__ inline unsigned short f32_to_bf16(float f) {
    union { float f; unsigned u; } v; v.f = f;
    unsigned u = v.u;
    unsigned r = u + 0x7FFF + ((u >> 16) & 1);
    return (unsigned short)(r >> 16);
}

// ---------------- embed MFMA (M=64, X direct-from-global) + weight-transpose tails ----
#define XS_P 136
__global__ __launch_bounds__(256) void embed_both_kernel(
        const float* __restrict__ xf, const float* __restrict__ wsf,   // [128][64] f32
        const float* __restrict__ xc, const float* __restrict__ wsc,   // [128][64] f32
        const float* __restrict__ bias_c,
        unsigned short* __restrict__ yf, unsigned short* __restrict__ yc,
        int nf, int nemb,
        const float* __restrict__ w_content, const float* __restrict__ w_coarse,
        const float* __restrict__ w_fineout,
        unsigned short* __restrict__ wconT, unsigned short* __restrict__ wcT,
        unsigned short* __restrict__ wfT) {
    int tid = threadIdx.x;

    if ((int)blockIdx.x >= nemb) {
        int idx = (blockIdx.x - nemb) * 256 + tid;   // 0..51199
        if (idx < 18432) {
            int n = idx / 576, k = idx - n * 576;
            float v = (n < 25) ? w_content[k * 25 + n] : 0.0f;
            wconT[idx] = f32_to_bf16(v);
        } else if (idx < 34816) {
            int j = idx - 18432;
            int o = j >> 7, k = j & 127;
            wcT[j] = f32_to_bf16(w_coarse[k * 128 + o]);
        } else {
            int j = idx - 34816;
            int o = j >> 7, k = j & 127;
            wfT[j] = f32_to_bf16(w_fineout[k * 128 + o]);
        }
        return;
    }

    __shared__ unsigned short Ws[64 * XS_P];   // 17.4 KB
    bool is_f = (int)blockIdx.x < nf;
    int blk = is_f ? blockIdx.x : (blockIdx.x - nf);
    const float* x = is_f ? xf : xc;
    const float* wsrcf = is_f ? wsf : wsc;
    const float* bias = is_f ? nullptr : bias_c;
    unsigned short* y = is_f ? yf : yc;
    size_t row0 = (size_t)blk * 64;

    for (int ci = tid; ci < 2048; ci += 256) {
        int k = ci >> 4;
        int n4 = (ci & 15) * 4;
        float4 v = *(const float4*)(wsrcf + k * 64 + n4);
        Ws[(n4 + 0) * XS_P + k] = f32_to_bf16(v.x);
        Ws[(n4 + 1) * XS_P + k] = f32_to_bf16(v.y);
        Ws[(n4 + 2) * XS_P + k] = f32_to_bf16(v.z);
        Ws[(n4 + 3) * XS_P + k] = f32_to_bf16(v.w);
    }
    __syncthreads();

    int wid = tid >> 6, lane = tid & 63;
    int lr = lane & 15, hi = lane >> 4, lk = hi * 8;

    int arow = wid * 16 + lr;
    const float* xr = x + (row0 + arow) * 128;

    floatx4 acc[4];
    #pragma unroll
    for (int ni = 0; ni < 4; ++ni)
        acc[ni] = (floatx4){0.f, 0.f, 0.f, 0.f};

    #pragma unroll
    for (int kk = 0; kk < 4; ++kk) {
        float4 a0 = *(const float4*)(xr + kk * 32 + lk);
        float4 a1 = *(const float4*)(xr + kk * 32 + lk + 4);
        unsigned short ah[8];
        ah[0] = f32_to_bf16(a0.x); ah[1] = f32_to_bf16(a0.y);
        ah[2] = f32_to_bf16(a0.z); ah[3] = f32_to_bf16(a0.w);
        ah[4] = f32_to_bf16(a1.x); ah[5] = f32_to_bf16(a1.y);
        ah[6] = f32_to_bf16(a1.z); ah[7] = f32_to_bf16(a1.w);
        short8 a = *(const short8*)ah;
        #pragma unroll
        for (int ni = 0; ni < 4; ++ni) {
            short8 bb = *(const short8*)(&Ws[(ni * 16 + lr) * XS_P + kk * 32 + lk]);
            acc[ni] = __builtin_amdgcn_mfma_f32_16x16x32_bf16(a, bb, acc[ni], 0, 0, 0);
        }
    }

    #pragma unroll
    for (int ni = 0; ni < 4; ++ni) {
        int col = ni * 16 + lr;
        float bs = bias ? bias[col] : 0.0f;
        #pragma unroll
        for (int j = 0; j < 4; ++j) {
            int row = wid * 16 + hi * 4 + j;
            y[(row0 + row) * EMB + col] = f32_to_bf16(acc[ni][j] + bs);
        }
    }
}

// ---------------- content conv MFMA (both resolutions), pad-32 output ----------------
#define SP 72
#define SB 584
__global__ __launch_bounds__(256) void content_both_kernel(
        const unsigned short* __restrict__ embf,
        const unsigned short* __restrict__ embc,
        const unsigned short* __restrict__ wT,   // bf16 [32][576]
        const float* __restrict__ bias,          // [25]
        float* __restrict__ yf, float* __restrict__ yc,   // [*,CST] padded
        int nf) {
    __shared__ unsigned short Es[6 * 34 * SP];
    __shared__ unsigned short Bs[32 * SB];
    int tid = threadIdx.x;
    bool is_f = (int)blockIdx.x < nf;
    int blk = is_f ? blockIdx.x : (blockIdx.x - nf);
    const unsigned short* emb = is_f ? embf : embc;
    float* y = is_f ? yf : yc;
    int HT = is_f ? 32 : 16;
    int WT = is_f ? 4 : 2;
    int Hh = is_f ? 128 : 64;
    int Ww = is_f ? 128 : 64;

    int bx = blk % WT;
    int t = blk / WT;
    int by = t % HT;
    int b = t / HT;

    for (int ci = tid; ci < 1632; ci += 256) {
        int pi = ci >> 3, e8 = ci & 7;
        int hy = pi / 34, hx = pi - hy * 34;
        int gy = by * 4 + hy - 1, gx = bx * 32 + hx - 1;
        uint4 v = {0u, 0u, 0u, 0u};
        if (gy >= 0 && gy < Hh && gx >= 0 && gx < Ww)
            v = *(const uint4*)(emb + (((size_t)(b * Hh + gy)) * Ww + gx) * EMB + e8 * 8);
        *(uint4*)(&Es[pi * SP + e8 * 8]) = v;
    }
    for (int ci = tid; ci < 2304; ci += 256) {
        int n = ci / 72, k8 = ci - n * 72;
        *(uint4*)(&Bs[n * SB + k8 * 8]) = *(const uint4*)(wT + n * 576 + k8 * 8);
    }
    __syncthreads();

    int wid = tid >> 6, lane = tid & 63;
    int lr = lane & 15, hi = lane >> 4, lk = hi * 8;

    floatx4 acc[2][2];
    #pragma unroll
    for (int mi = 0; mi < 2; ++mi)
        #pragma unroll
        for (int ni = 0; ni < 2; ++ni)
            acc[mi][ni] = (floatx4){0.f, 0.f, 0.f, 0.f};

    #pragma unroll
    for (int tap = 0; tap < 9; ++tap) {
        int dy = tap / 3, dx = tap - dy * 3;
        #pragma unroll
        for (int ks = 0; ks < 2; ++ks) {
            short8 a[2], bb[2];
            #pragma unroll
            for (int mi = 0; mi < 2; ++mi) {
                int p = wid * 32 + mi * 16 + lr;
                int r = p >> 5, c = p & 31;
                a[mi] = *(const short8*)(&Es[((r + dy) * 34 + (c + dx)) * SP + ks * 32 + lk]);
            }
            #pragma unroll
            for (int ni = 0; ni < 2; ++ni)
                bb[ni] = *(const short8*)(&Bs[(ni * 16 + lr) * SB + tap * 64 + ks * 32 + lk]);
            #pragma unroll
            for (int mi = 0; mi < 2; ++mi)
                #pragma unroll
                for (int ni = 0; ni < 2; ++ni)
                    acc[mi][ni] = __builtin_amdgcn_mfma_f32_16x16x32_bf16(a[mi], bb[ni], acc[mi][ni], 0, 0, 0);
        }
    }

    #pragma unroll
    for (int mi = 0; mi < 2; ++mi) {
        #pragma unroll
        for (int ni = 0; ni < 2; ++ni) {
            int n = ni * 16 + lr;
            if (n < KK) {
                float bs = bias[n];
                #pragma unroll
                for (int j = 0; j < 4; ++j) {
                    int p = wid * 32 + mi * 16 + hi * 4 + j;
                    int r = p >> 5, c = p & 31;
                    size_t gq = ((size_t)(b * Hh + by * 4 + r)) * Ww + bx * 32 + c;
                    y[gq * CST + n] = acc[mi][ni][j] + bs;
                }
            }
        }
    }
}

// ================ fused carafe + gate + final double-GEMM + blend (M=32) ================
// Block = 2x4 coarse tile = 32 fine pixels = one M=32 GEMM tile. 1024 blocks,
// 43.5 KB LDS -> 3 blocks/CU resident; per-block chain is ~half of the M=64 version.
// LDS: [0,24576) patches f32 [48][128] -> overlaid by Ws [128][LDSP] (34816 B)
//      [24576,28672) wsm [32][32] f32  -> dead before Ws overlay reaches it
//      [34816,34848) g_lds [8]         -> beyond Ws end
//      [34848,43552) Xs [32][LDSP] bf16
#define LDSP 136
__global__ __launch_bounds__(256) void carafe_final_kernel(
        const float* __restrict__ coarse,   // [B,64,64,128]
        const float* __restrict__ f_conv,   // [B,128,128,CST]
        const float* __restrict__ c_conv,   // [B,64,64,CST]
        const float* __restrict__ w_gate,   // [128]
        const float* __restrict__ b_gate,   // [1]
        const unsigned short* __restrict__ WcT,  // bf16 [o][k]
        const unsigned short* __restrict__ WfT,  // bf16 [p][o]
        const float* __restrict__ b_coarse,
        const float* __restrict__ b_fineout,
        float* __restrict__ out) {
    __shared__ __align__(16) char smem[43552];
    float* patches = (float*)smem;                        // [48][128]
    float* wsm     = (float*)(smem + 24576);              // [32][32]
    float* g_lds   = (float*)(smem + 34816);              // [8]
    unsigned short* Ws = (unsigned short*)smem;           // [128][LDSP] overlay
    unsigned short* Xs = (unsigned short*)(smem + 34848); // [32][LDSP]

    const int h = 64, w = 64, H2 = 128, W2 = 128;
    int tid = threadIdx.x;
    int blk = blockIdx.x;
    int cx0 = (blk & 15) * 4;            // coarse col start (4 cols)
    int cy0 = ((blk >> 4) & 31) * 2;     // coarse row start (2 rows)
    int b = blk >> 9;

    // ---- stage 6x8 coarse halo region (f32), 1536 float4 ----
    for (int ci = tid; ci < 1536; ci += 256) {
        int pi = ci >> 5;                 // 0..47
        int c4 = (ci & 31) << 2;
        int sy = cy0 - 2 + (pi >> 3);
        int sx = cx0 - 2 + (pi & 7);
        float4 v = {0.f, 0.f, 0.f, 0.f};
        if (sy >= 0 && sy < h && sx >= 0 && sx < w)
            v = *(const float4*)(coarse + (((size_t)(b * h + sy)) * w + sx) * CC + c4);
        *(float4*)(&patches[pi * 128 + c4]) = v;
    }

    // ---- softmax for 32 fine pixels (wave-parallel, 2 px per pass, 4 passes) ----
    int wid = tid >> 6, lane = tid & 63;
    {
        int k = lane & 31;
        #pragma unroll
        for (int pass = 0; pass < 4; ++pass) {
            int fp = wid * 8 + pass * 2 + (lane >> 5);
            int fry = fp >> 3, frx = fp & 7;
            int fy = 2 * cy0 + fry, fx = 2 * cx0 + frx;
            int cy = cy0 + (fry >> 1), cx = cx0 + (frx >> 1);
            size_t fq = ((size_t)(b * H2 + fy)) * W2 + fx;
            size_t cq = ((size_t)(b * h + cy)) * w + cx;
            float v = -1e30f;
            if (k < KK)
                v = f_conv[fq * CST + k] + c_conv[cq * CST + k];
            float m = v;
            #pragma unroll
            for (int mask = 16; mask > 0; mask >>= 1)
                m = fmaxf(m, __shfl_xor(m, mask, 32));
            float e = (k < KK) ? __expf(v - m) : 0.0f;
            float s = e;
            #pragma unroll
            for (int mask = 16; mask > 0; mask >>= 1)
                s += __shfl_xor(s, mask, 32);
            wsm[fp * 32 + k] = e / s;    // rows 25..31 = exact 0.0
        }
    }
    __syncthreads();

    // ---- gate for the 8 owned coarse pixels (from staged centers) ----
    if (tid < 128) {
        int cp = tid >> 4;        // 0..7
        int part = tid & 15;
        int ry = cp >> 2, rx = cp & 3;
        int pidx = (ry + 2) * 8 + (rx + 2);
        const float* pc = patches + pidx * 128 + part * 8;
        float4 a0 = *(const float4*)(pc);
        float4 a1 = *(const float4*)(pc + 4);
        float4 g0 = *(const float4*)(w_gate + part * 8);
        float4 g1 = *(const float4*)(w_gate + part * 8 + 4);
        float acc = a0.x * g0.x + a0.y * g0.y + a0.z * g0.z + a0.w * g0.w
                  + a1.x * g1.x + a1.y * g1.y + a1.z * g1.z + a1.w * g1.w;
        #pragma unroll
        for (int mask = 8; mask > 0; mask >>= 1)
            acc += __shfl_xor(acc, mask, 16);
        if (part == 0) {
            float z = acc + b_gate[0];
            g_lds[cp] = 1.0f / (1.0f + __expf(-z));
        }
    }

    // ---- FAITHFUL gather, 4 fine px per thread per coarse pixel, 4 iters ----
    {
        int c   = tid & 127;
        int cpg = tid >> 7;         // 0..1
        int offs[28];
        int c25 = c * 25;
        #pragma unroll
        for (int j = 0; j < 28; ++j) {
            int i = c25 + j;
            int p = i >> 7;
            int ch = i & 127;
            int pd = (p * 205) >> 10;   // p/5
            int pm = p - pd * 5;
            offs[j] = (pd * 8 + pm) * 128 + ch;
        }
        #pragma unroll
        for (int it = 0; it < 4; ++it) {
            int cp = cpg * 4 + it;
            int ry = cp >> 2, rx = cp & 3;
            int cpbase = (ry * 8 + rx) * 128;
            int fpA = (2 * ry) * 8 + 2 * rx;   // 4 fine px: fpA, fpA+1, fpA+8, fpA+9
            float a00 = 0.f, a01 = 0.f, a10 = 0.f, a11 = 0.f;
            #pragma unroll
            for (int j4 = 0; j4 < 7; ++j4) {
                float4 wA = *(const float4*)(&wsm[fpA * 32 + j4 * 4]);
                float4 wB = *(const float4*)(&wsm[(fpA + 1) * 32 + j4 * 4]);
                float4 wC = *(const float4*)(&wsm[(fpA + 8) * 32 + j4 * 4]);
                float4 wD = *(const float4*)(&wsm[(fpA + 9) * 32 + j4 * 4]);
                #pragma unroll
                for (int jj = 0; jj < 4; ++jj) {
                    float pv = patches[cpbase + offs[j4 * 4 + jj]];
                    float wa = (jj == 0) ? wA.x : (jj == 1) ? wA.y : (jj == 2) ? wA.z : wA.w;
                    float wb = (jj == 0) ? wB.x : (jj == 1) ? wB.y : (jj == 2) ? wB.z : wB.w;
                    float wc = (jj == 0) ? wC.x : (jj == 1) ? wC.y : (jj == 2) ? wC.z : wC.w;
                    float wd = (jj == 0) ? wD.x : (jj == 1) ? wD.y : (jj == 2) ? wD.z : wD.w;
                    a00 += wa * pv;
                    a01 += wb * pv;
                    a10 += wc * pv;
                    a11 += wd * pv;
                }
            }
            Xs[fpA * LDSP + c]       = f32_to_bf16(a00);
            Xs[(fpA + 1) * LDSP + c] = f32_to_bf16(a01);
            Xs[(fpA + 8) * LDSP + c] = f32_to_bf16(a10);
            Xs[(fpA + 9) * LDSP + c] = f32_to_bf16(a11);
        }
    }
    __syncthreads();     // gather done; patches/wsm dead

    {
        const uint4* wsrc = (const uint4*)WcT;
        for (int ci = tid; ci < 2048; ci += 256) {
            int r = ci >> 4, c = ci & 15;
            *(uint4*)(&Ws[r * LDSP + c * 8]) = wsrc[ci];
        }
    }
    __syncthreads();

    int wm = wid >> 1, wn = wid & 1;
    int lr = lane & 15;
    int lk = (lane >> 4) * 8;
    int lrow4 = (lane >> 4) * 4;

    floatx4 acc1[4];
    #pragma unroll
    for (int ni = 0; ni < 4; ++ni)
        acc1[ni] = (floatx4){0.f, 0.f, 0.f, 0.f};

    #pragma unroll
    for (int kk = 0; kk < 128; kk += 32) {
        short8 a = *(const short8*)(&Xs[(wm * 16 + lr) * LDSP + kk + lk]);
        short8 bb[4];
        #pragma unroll
        for (int ni = 0; ni < 4; ++ni)
            bb[ni] = *(const short8*)(&Ws[(wn * 64 + ni * 16 + lr) * LDSP + kk + lk]);
        #pragma unroll
        for (int ni = 0; ni < 4; ++ni)
            acc1[ni] = __builtin_amdgcn_mfma_f32_16x16x32_bf16(a, bb[ni], acc1[ni], 0, 0, 0);
    }
    __syncthreads();     // GEMM1 done reading Ws & Xs

    {
        const uint4* wsrc = (const uint4*)WfT;
        for (int ci = tid; ci < 2048; ci += 256) {
            int r = ci >> 4, c = ci & 15;
            *(uint4*)(&Ws[r * LDSP + c * 8]) = wsrc[ci];
        }
    }
    #pragma unroll
    for (int ni = 0; ni < 4; ++ni) {
        int col = wn * 64 + ni * 16 + lr;
        float bc = b_coarse[col];
        #pragma unroll
        for (int j = 0; j < 4; ++j) {
            int row = wm * 16 + lrow4 + j;
            float v = acc1[ni][j] + bc;
            acc1[ni][j] = v;
            Xs[row * LDSP + col] = f32_to_bf16(v);
        }
    }
    __syncthreads();

    floatx4 acc2[4];
    #pragma unroll
    for (int ni = 0; ni < 4; ++ni)
        acc2[ni] = (floatx4){0.f, 0.f, 0.f, 0.f};

    #pragma unroll
    for (int kk = 0; kk < 128; kk += 32) {
        short8 a = *(const short8*)(&Xs[(wm * 16 + lr) * LDSP + kk + lk]);
        short8 bb[4];
        #pragma unroll
        for (int ni = 0; ni < 4; ++ni)
            bb[ni] = *(const short8*)(&Ws[(wn * 64 + ni * 16 + lr) * LDSP + kk + lk]);
        #pragma unroll
        for (int ni = 0; ni < 4; ++ni)
            acc2[ni] = __builtin_amdgcn_mfma_f32_16x16x32_bf16(a, bb[ni], acc2[ni], 0, 0, 0);
    }

    // ---- epilogue: blend with gate, scatter to global ----
    #pragma unroll
    for (int ni = 0; ni < 4; ++ni) {
        int col = wn * 64 + ni * 16 + lr;
        float bf = b_fineout[col];
        #pragma unroll
        for (int j = 0; j < 4; ++j) {
            int row = wm * 16 + lrow4 + j;    // local fine pixel 0..31
            int fry = row >> 3, frx = row & 7;
            float g = g_lds[((fry >> 1) << 2) + (frx >> 1)];
            int fy = 2 * cy0 + fry, fx = 2 * cx0 + frx;
            size_t q = ((size_t)(b * H2 + fy)) * W2 + fx;
            float co = acc1[ni][j];
            float fo = acc2[ni][j] + bf;
            out[q * FILTERS + col] = g * fo + (1.0f - g) * co;
        }
    }
}

extern "C" void kernel_launch(void* const* d_in, const int* in_sizes, int n_in,
                              void* d_out, int out_size, void* d_ws, size_t ws_size,
                              hipStream_t stream) {
    const float* fine      = (const float*)d_in[0];
    const float* coarse    = (const float*)d_in[1];
    const float* w_gate    = (const float*)d_in[2];
    const float* b_gate    = (const float*)d_in[3];
    const float* w_sfine   = (const float*)d_in[4];
    const float* w_scoarse = (const float*)d_in[5];
    const float* b_scoarse = (const float*)d_in[6];
    const float* w_content = (const float*)d_in[7];
    const float* b_content = (const float*)d_in[8];
    const float* w_coarse  = (const float*)d_in[9];
    const float* b_coarse  = (const float*)d_in[10];
    const float* w_fineout = (const float*)d_in[11];
    const float* b_fineout = (const float*)d_in[12];
    float* out = (float*)d_out;

    const int B = 2, H = 128, W = 128, h = 64, w = 64;
    const int MF = B * H * W;   // 32768
    const int MC = B * h * w;   // 8192

    char* ws = (char*)d_ws;
    size_t off = 0;
    auto alloc = [&](size_t bytes) {
        void* p = ws + off;
        off = (off + bytes + 255) & ~(size_t)255;
        return p;
    };
    unsigned short* f_emb    = (unsigned short*)alloc((size_t)MF * EMB * 2);
    unsigned short* c_emb    = (unsigned short*)alloc((size_t)MC * EMB * 2);
    float* f_conv            = (float*)alloc((size_t)MF * CST * 4);
    float* c_conv            = (float*)alloc((size_t)MC * CST * 4);
    unsigned short* wconT    = (unsigned short*)alloc(32 * 576 * 2);
    unsigned short* wcT      = (unsigned short*)alloc(128 * 128 * 2);
    unsigned short* wfT      = (unsigned short*)alloc(128 * 128 * 2);

    const int NEF = MF / 64;          // 512 fine embed blocks
    const int NEC = MC / 64;          // 128 coarse embed blocks
    const int NEB = NEF + NEC;        // 640 embed blocks
    const int NWT = 200;              // 51200 transpose elems / 256
    const int NCF = B * (H / 4) * (W / 32);   // 256 fine content blocks
    const int NCC = B * (h / 4) * (w / 32);   // 64 coarse content blocks

    embed_both_kernel<<<NEB + NWT, 256, 0, stream>>>(fine, w_sfine, coarse, w_scoarse, b_scoarse,
                                                     f_emb, c_emb, NEF, NEB,
                                                     w_content, w_coarse, w_fineout,
                                                     wconT, wcT, wfT);
    content_both_kernel<<<NCF + NCC, 256, 0, stream>>>(f_emb, c_emb, wconT, b_content,
                                                       f_conv, c_conv, NCF);
    carafe_final_kernel<<<B * 32 * 16, 256, 0, stream>>>(coarse, f_conv, c_conv, w_gate, b_gate,
                                                         wcT, wfT, b_coarse, b_fineout, out);
}

// Round 14
// 47.310 us; speedup vs baseline: 1.0330x; 1.0330x over previous
//
#include <hip/hip_runtime.h>
#include <hip/hip_bf16.h>
#include <cstdint>
#include <cstddef>

#define KSZ 5
#define KK 25
#define EMB 64
#define CC 128
#define FILTERS 128
#define CST 32   // padded conv-out stride (f_conv/c_conv rows, 128B aligned)

typedef __attribute__((ext_vector_type(8))) short short8;
typedef __attribute__((ext_vector_type(4))) float floatx4;

__device__ inline unsigned short f32_to_bf16(float f) {
    union { float f; unsigned u; } v; v.f = f;
    unsigned u = v.u;
    unsigned r = u + 0x7FFF + ((u >> 16) & 1);
    return (unsigned short)(r >> 16);
}

// ---------------- embed MFMA (M=64, X direct-from-global) + weight-transpose tails ----
#define XS_P 136
__global__ __launch_bounds__(256) void embed_both_kernel(
        const float* __restrict__ xf, const float* __restrict__ wsf,   // [128][64] f32
        const float* __restrict__ xc, const float* __restrict__ wsc,   // [128][64] f32
        const float* __restrict__ bias_c,
        unsigned short* __restrict__ yf, unsigned short* __restrict__ yc,
        int nf, int nemb,
        const float* __restrict__ w_content, const float* __restrict__ w_coarse,
        const float* __restrict__ w_fineout,
        unsigned short* __restrict__ wconT, unsigned short* __restrict__ wcT,
        unsigned short* __restrict__ wfT) {
    int tid = threadIdx.x;

    if ((int)blockIdx.x >= nemb) {
        int idx = (blockIdx.x - nemb) * 256 + tid;   // 0..51199
        if (idx < 18432) {
            int n = idx / 576, k = idx - n * 576;
            float v = (n < 25) ? w_content[k * 25 + n] : 0.0f;
            wconT[idx] = f32_to_bf16(v);
        } else if (idx < 34816) {
            int j = idx - 18432;
            int o = j >> 7, k = j & 127;
            wcT[j] = f32_to_bf16(w_coarse[k * 128 + o]);
        } else {
            int j = idx - 34816;
            int o = j >> 7, k = j & 127;
            wfT[j] = f32_to_bf16(w_fineout[k * 128 + o]);
        }
        return;
    }

    __shared__ unsigned short Ws[64 * XS_P];   // 17.4 KB
    bool is_f = (int)blockIdx.x < nf;
    int blk = is_f ? blockIdx.x : (blockIdx.x - nf);
    const float* x = is_f ? xf : xc;
    const float* wsrcf = is_f ? wsf : wsc;
    const float* bias = is_f ? nullptr : bias_c;
    unsigned short* y = is_f ? yf : yc;
    size_t row0 = (size_t)blk * 64;

    for (int ci = tid; ci < 2048; ci += 256) {
        int k = ci >> 4;
        int n4 = (ci & 15) * 4;
        float4 v = *(const float4*)(wsrcf + k * 64 + n4);
        Ws[(n4 + 0) * XS_P + k] = f32_to_bf16(v.x);
        Ws[(n4 + 1) * XS_P + k] = f32_to_bf16(v.y);
        Ws[(n4 + 2) * XS_P + k] = f32_to_bf16(v.z);
        Ws[(n4 + 3) * XS_P + k] = f32_to_bf16(v.w);
    }
    __syncthreads();

    int wid = tid >> 6, lane = tid & 63;
    int lr = lane & 15, hi = lane >> 4, lk = hi * 8;

    int arow = wid * 16 + lr;
    const float* xr = x + (row0 + arow) * 128;

    floatx4 acc[4];
    #pragma unroll
    for (int ni = 0; ni < 4; ++ni)
        acc[ni] = (floatx4){0.f, 0.f, 0.f, 0.f};

    #pragma unroll
    for (int kk = 0; kk < 4; ++kk) {
        float4 a0 = *(const float4*)(xr + kk * 32 + lk);
        float4 a1 = *(const float4*)(xr + kk * 32 + lk + 4);
        unsigned short ah[8];
        ah[0] = f32_to_bf16(a0.x); ah[1] = f32_to_bf16(a0.y);
        ah[2] = f32_to_bf16(a0.z); ah[3] = f32_to_bf16(a0.w);
        ah[4] = f32_to_bf16(a1.x); ah[5] = f32_to_bf16(a1.y);
        ah[6] = f32_to_bf16(a1.z); ah[7] = f32_to_bf16(a1.w);
        short8 a = *(const short8*)ah;
        #pragma unroll
        for (int ni = 0; ni < 4; ++ni) {
            short8 bb = *(const short8*)(&Ws[(ni * 16 + lr) * XS_P + kk * 32 + lk]);
            acc[ni] = __builtin_amdgcn_mfma_f32_16x16x32_bf16(a, bb, acc[ni], 0, 0, 0);
        }
    }

    #pragma unroll
    for (int ni = 0; ni < 4; ++ni) {
        int col = ni * 16 + lr;
        float bs = bias ? bias[col] : 0.0f;
        #pragma unroll
        for (int j = 0; j < 4; ++j) {
            int row = wid * 16 + hi * 4 + j;
            y[(row0 + row) * EMB + col] = f32_to_bf16(acc[ni][j] + bs);
        }
    }
}

// ---------------- content conv MFMA (both resolutions), pad-32 output ----------------
#define SP 72
#define SB 584
__global__ __launch_bounds__(256) void content_both_kernel(
        const unsigned short* __restrict__ embf,
        const unsigned short* __restrict__ embc,
        const unsigned short* __restrict__ wT,   // bf16 [32][576]
        const float* __restrict__ bias,          // [25]
        float* __restrict__ yf, float* __restrict__ yc,   // [*,CST] padded
        int nf) {
    __shared__ unsigned short Es[6 * 34 * SP];
    __shared__ unsigned short Bs[32 * SB];
    int tid = threadIdx.x;
    bool is_f = (int)blockIdx.x < nf;
    int blk = is_f ? blockIdx.x : (blockIdx.x - nf);
    const unsigned short* emb = is_f ? embf : embc;
    float* y = is_f ? yf : yc;
    int HT = is_f ? 32 : 16;
    int WT = is_f ? 4 : 2;
    int Hh = is_f ? 128 : 64;
    int Ww = is_f ? 128 : 64;

    int bx = blk % WT;
    int t = blk / WT;
    int by = t % HT;
    int b = t / HT;

    for (int ci = tid; ci < 1632; ci += 256) {
        int pi = ci >> 3, e8 = ci & 7;
        int hy = pi / 34, hx = pi - hy * 34;
        int gy = by * 4 + hy - 1, gx = bx * 32 + hx - 1;
        uint4 v = {0u, 0u, 0u, 0u};
        if (gy >= 0 && gy < Hh && gx >= 0 && gx < Ww)
            v = *(const uint4*)(emb + (((size_t)(b * Hh + gy)) * Ww + gx) * EMB + e8 * 8);
        *(uint4*)(&Es[pi * SP + e8 * 8]) = v;
    }
    for (int ci = tid; ci < 2304; ci += 256) {
        int n = ci / 72, k8 = ci - n * 72;
        *(uint4*)(&Bs[n * SB + k8 * 8]) = *(const uint4*)(wT + n * 576 + k8 * 8);
    }
    __syncthreads();

    int wid = tid >> 6, lane = tid & 63;
    int lr = lane & 15, hi = lane >> 4, lk = hi * 8;

    floatx4 acc[2][2];
    #pragma unroll
    for (int mi = 0; mi < 2; ++mi)
        #pragma unroll
        for (int ni = 0; ni < 2; ++ni)
            acc[mi][ni] = (floatx4){0.f, 0.f, 0.f, 0.f};

    #pragma unroll
    for (int tap = 0; tap < 9; ++tap) {
        int dy = tap / 3, dx = tap - dy * 3;
        #pragma unroll
        for (int ks = 0; ks < 2; ++ks) {
            short8 a[2], bb[2];
            #pragma unroll
            for (int mi = 0; mi < 2; ++mi) {
                int p = wid * 32 + mi * 16 + lr;
                int r = p >> 5, c = p & 31;
                a[mi] = *(const short8*)(&Es[((r + dy) * 34 + (c + dx)) * SP + ks * 32 + lk]);
            }
            #pragma unroll
            for (int ni = 0; ni < 2; ++ni)
                bb[ni] = *(const short8*)(&Bs[(ni * 16 + lr) * SB + tap * 64 + ks * 32 + lk]);
            #pragma unroll
            for (int mi = 0; mi < 2; ++mi)
                #pragma unroll
                for (int ni = 0; ni < 2; ++ni)
                    acc[mi][ni] = __builtin_amdgcn_mfma_f32_16x16x32_bf16(a[mi], bb[ni], acc[mi][ni], 0, 0, 0);
        }
    }

    #pragma unroll
    for (int mi = 0; mi < 2; ++mi) {
        #pragma unroll
        for (int ni = 0; ni < 2; ++ni) {
            int n = ni * 16 + lr;
            if (n < KK) {
                float bs = bias[n];
                #pragma unroll
                for (int j = 0; j < 4; ++j) {
                    int p = wid * 32 + mi * 16 + hi * 4 + j;
                    int r = p >> 5, c = p & 31;
                    size_t gq = ((size_t)(b * Hh + by * 4 + r)) * Ww + bx * 32 + c;
                    y[gq * CST + n] = acc[mi][ni][j] + bs;
                }
            }
        }
    }
}

// ================ fused carafe + gate + final double-GEMM + blend (M=64) ================
#define LDSP 136
__global__ __launch_bounds__(256) void carafe_final_kernel(
        const float* __restrict__ coarse,   // [B,64,64,128]
        const float* __restrict__ f_conv,   // [B,128,128,CST]
        const float* __restrict__ c_conv,   // [B,64,64,CST]
        const float* __restrict__ w_gate,   // [128]
        const float* __restrict__ b_gate,   // [1]
        const unsigned short* __restrict__ WcT,  // bf16 [o][k]
        const unsigned short* __restrict__ WfT,  // bf16 [p][o]
        const float* __restrict__ b_coarse,
        const float* __restrict__ b_fineout,
        float* __restrict__ out) {
    __shared__ __align__(16) char smem[58624];
    float* patches = (float*)smem;                        // [64][128]
    float* wsm     = (float*)(smem + 32768);              // [64][32]
    float* g_lds   = (float*)(smem + 40960);              // [16]
    unsigned short* Ws = (unsigned short*)smem;           // [128][LDSP] overlay
    unsigned short* Xs = (unsigned short*)(smem + 41216); // [64][LDSP]

    const int h = 64, w = 64, H2 = 128, W2 = 128;
    int tid = threadIdx.x;
    int blk = blockIdx.x;
    int cx0 = (blk & 15) * 4;
    int cy0 = ((blk >> 4) & 15) * 4;
    int b = blk >> 8;

    for (int ci = tid; ci < 2048; ci += 256) {
        int pi = ci >> 5;
        int c4 = (ci & 31) << 2;
        int sy = cy0 - 2 + (pi >> 3);
        int sx = cx0 - 2 + (pi & 7);
        float4 v = {0.f, 0.f, 0.f, 0.f};
        if (sy >= 0 && sy < h && sx >= 0 && sx < w)
            v = *(const float4*)(coarse + (((size_t)(b * h + sy)) * w + sx) * CC + c4);
        *(float4*)(&patches[pi * 128 + c4]) = v;
    }

    int wid = tid >> 6, lane = tid & 63;
    {
        int k = lane & 31;
        #pragma unroll
        for (int pass = 0; pass < 8; ++pass) {
            int fp = wid * 16 + pass * 2 + (lane >> 5);
            int fry = fp >> 3, frx = fp & 7;
            int fy = 2 * cy0 + fry, fx = 2 * cx0 + frx;
            int cy = cy0 + (fry >> 1), cx = cx0 + (frx >> 1);
            size_t fq = ((size_t)(b * H2 + fy)) * W2 + fx;
            size_t cq = ((size_t)(b * h + cy)) * w + cx;
            float v = -1e30f;
            if (k < KK)
                v = f_conv[fq * CST + k] + c_conv[cq * CST + k];
            float m = v;
            #pragma unroll
            for (int mask = 16; mask > 0; mask >>= 1)
                m = fmaxf(m, __shfl_xor(m, mask, 32));
            float e = (k < KK) ? __expf(v - m) : 0.0f;
            float s = e;
            #pragma unroll
            for (int mask = 16; mask > 0; mask >>= 1)
                s += __shfl_xor(s, mask, 32);
            wsm[fp * 32 + k] = e / s;    // rows 25..31 = exact 0.0
        }
    }
    __syncthreads();

    {
        int cp = tid >> 4;
        int part = tid & 15;
        int pidx = ((cp >> 2) + 2) * 8 + (cp & 3) + 2;
        const float* pc = patches + pidx * 128 + part * 8;
        float4 a0 = *(const float4*)(pc);
        float4 a1 = *(const float4*)(pc + 4);
        float4 g0 = *(const float4*)(w_gate + part * 8);
        float4 g1 = *(const float4*)(w_gate + part * 8 + 4);
        float acc = a0.x * g0.x + a0.y * g0.y + a0.z * g0.z + a0.w * g0.w
                  + a1.x * g1.x + a1.y * g1.y + a1.z * g1.z + a1.w * g1.w;
        #pragma unroll
        for (int mask = 8; mask > 0; mask >>= 1)
            acc += __shfl_xor(acc, mask, 16);
        if (part == 0) {
            float z = acc + b_gate[0];
            g_lds[cp] = 1.0f / (1.0f + __expf(-z));
        }
    }

    // ---- FAITHFUL gather, 4 fine px per thread per coarse pixel ----
    {
        int c   = tid & 127;
        int cpg = tid >> 7;
        int offs[28];
        int c25 = c * 25;
        #pragma unroll
        for (int j = 0; j < 28; ++j) {
            int i = c25 + j;
            int p = i >> 7;
            int ch = i & 127;
            int pd = (p * 205) >> 10;   // p/5
            int pm = p - pd * 5;
            offs[j] = (pd * 8 + pm) * 128 + ch;
        }
        #pragma unroll
        for (int it = 0; it < 8; ++it) {
            int cp = cpg * 8 + it;
            int ry = cp >> 2, rx = cp & 3;
            int cpbase = (ry * 8 + rx) * 128;
            int fpA = (2 * ry) * 8 + 2 * rx;   // 4 fine px: fpA, fpA+1, fpA+8, fpA+9
            float a00 = 0.f, a01 = 0.f, a10 = 0.f, a11 = 0.f;
            #pragma unroll
            for (int j4 = 0; j4 < 7; ++j4) {
                float4 wA = *(const float4*)(&wsm[fpA * 32 + j4 * 4]);
                float4 wB = *(const float4*)(&wsm[(fpA + 1) * 32 + j4 * 4]);
                float4 wC = *(const float4*)(&wsm[(fpA + 8) * 32 + j4 * 4]);
                float4 wD = *(const float4*)(&wsm[(fpA + 9) * 32 + j4 * 4]);
                #pragma unroll
                for (int jj = 0; jj < 4; ++jj) {
                    float pv = patches[cpbase + offs[j4 * 4 + jj]];
                    float wa = (jj == 0) ? wA.x : (jj == 1) ? wA.y : (jj == 2) ? wA.z : wA.w;
                    float wb = (jj == 0) ? wB.x : (jj == 1) ? wB.y : (jj == 2) ? wB.z : wB.w;
                    float wc = (jj == 0) ? wC.x : (jj == 1) ? wC.y : (jj == 2) ? wC.z : wC.w;
                    float wd = (jj == 0) ? wD.x : (jj == 1) ? wD.y : (jj == 2) ? wD.z : wD.w;
                    a00 += wa * pv;
                    a01 += wb * pv;
                    a10 += wc * pv;
                    a11 += wd * pv;
                }
            }
            Xs[fpA * LDSP + c]       = f32_to_bf16(a00);
            Xs[(fpA + 1) * LDSP + c] = f32_to_bf16(a01);
            Xs[(fpA + 8) * LDSP + c] = f32_to_bf16(a10);
            Xs[(fpA + 9) * LDSP + c] = f32_to_bf16(a11);
        }
    }
    __syncthreads();

    {
        const uint4* wsrc = (const uint4*)WcT;
        for (int ci = tid; ci < 2048; ci += 256) {
            int r = ci >> 4, c = ci & 15;
            *(uint4*)(&Ws[r * LDSP + c * 8]) = wsrc[ci];
        }
    }
    __syncthreads();

    int wm = wid >> 1, wn = wid & 1;
    int lr = lane & 15;
    int lk = (lane >> 4) * 8;
    int lrow4 = (lane >> 4) * 4;

    floatx4 acc1[2][4];
    #pragma unroll
    for (int mi = 0; mi < 2; ++mi)
        #pragma unroll
        for (int ni = 0; ni < 4; ++ni)
            acc1[mi][ni] = (floatx4){0.f, 0.f, 0.f, 0.f};

    #pragma unroll
    for (int kk = 0; kk < 128; kk += 32) {
        short8 a[2], bb[4];
        #pragma unroll
        for (int mi = 0; mi < 2; ++mi)
            a[mi] = *(const short8*)(&Xs[(wm * 32 + mi * 16 + lr) * LDSP + kk + lk]);
        #pragma unroll
        for (int ni = 0; ni < 4; ++ni)
            bb[ni] = *(const short8*)(&Ws[(wn * 64 + ni * 16 + lr) * LDSP + kk + lk]);
        #pragma unroll
        for (int mi = 0; mi < 2; ++mi)
            #pragma unroll
            for (int ni = 0; ni < 4; ++ni)
                acc1[mi][ni] = __builtin_amdgcn_mfma_f32_16x16x32_bf16(a[mi], bb[ni], acc1[mi][ni], 0, 0, 0);
    }
    __syncthreads();

    {
        const uint4* wsrc = (const uint4*)WfT;
        for (int ci = tid; ci < 2048; ci += 256) {
            int r = ci >> 4, c = ci & 15;
            *(uint4*)(&Ws[r * LDSP + c * 8]) = wsrc[ci];
        }
    }
    #pragma unroll
    for (int mi = 0; mi < 2; ++mi) {
        #pragma unroll
        for (int ni = 0; ni < 4; ++ni) {
            int col = wn * 64 + ni * 16 + lr;
            float bc = b_coarse[col];
            #pragma unroll
            for (int j = 0; j < 4; ++j) {
                int row = wm * 32 + mi * 16 + lrow4 + j;
                float v = acc1[mi][ni][j] + bc;
                acc1[mi][ni][j] = v;
                Xs[row * LDSP + col] = f32_to_bf16(v);
            }
        }
    }
    __syncthreads();

    floatx4 acc2[2][4];
    #pragma unroll
    for (int mi = 0; mi < 2; ++mi)
        #pragma unroll
        for (int ni = 0; ni < 4; ++ni)
            acc2[mi][ni] = (floatx4){0.f, 0.f, 0.f, 0.f};

    #pragma unroll
    for (int kk = 0; kk < 128; kk += 32) {
        short8 a[2], bb[4];
        #pragma unroll
        for (int mi = 0; mi < 2; ++mi)
            a[mi] = *(const short8*)(&Xs[(wm * 32 + mi * 16 + lr) * LDSP + kk + lk]);
        #pragma unroll
        for (int ni = 0; ni < 4; ++ni)
            bb[ni] = *(const short8*)(&Ws[(wn * 64 + ni * 16 + lr) * LDSP + kk + lk]);
        #pragma unroll
        for (int mi = 0; mi < 2; ++mi)
            #pragma unroll
            for (int ni = 0; ni < 4; ++ni)
                acc2[mi][ni] = __builtin_amdgcn_mfma_f32_16x16x32_bf16(a[mi], bb[ni], acc2[mi][ni], 0, 0, 0);
    }

    #pragma unroll
    for (int mi = 0; mi < 2; ++mi) {
        #pragma unroll
        for (int ni = 0; ni < 4; ++ni) {
            int col = wn * 64 + ni * 16 + lr;
            float bf = b_fineout[col];
            #pragma unroll
            for (int j = 0; j < 4; ++j) {
                int row = wm * 32 + mi * 16 + lrow4 + j;
                int fry = row >> 3, frx = row & 7;
                float g = g_lds[((fry >> 1) << 2) + (frx >> 1)];
                int fy = 2 * cy0 + fry, fx = 2 * cx0 + frx;
                size_t q = ((size_t)(b * H2 + fy)) * W2 + fx;
                float co = acc1[mi][ni][j];
                float fo = acc2[mi][ni][j] + bf;
                out[q * FILTERS + col] = g * fo + (1.0f - g) * co;
            }
        }
    }
}

extern "C" void kernel_launch(void* const* d_in, const int* in_sizes, int n_in,
                              void* d_out, int out_size, void* d_ws, size_t ws_size,
                              hipStream_t stream) {
    const float* fine      = (const float*)d_in[0];
    const float* coarse    = (const float*)d_in[1];
    const float* w_gate    = (const float*)d_in[2];
    const float* b_gate    = (const float*)d_in[3];
    const float* w_sfine   = (const float*)d_in[4];
    const float* w_scoarse = (const float*)d_in[5];
    const float* b_scoarse = (const float*)d_in[6];
    const float* w_content = (const float*)d_in[7];
    const float* b_content = (const float*)d_in[8];
    const float* w_coarse  = (const float*)d_in[9];
    const float* b_coarse  = (const float*)d_in[10];
    const float* w_fineout = (const float*)d_in[11];
    const float* b_fineout = (const float*)d_in[12];
    float* out = (float*)d_out;

    const int B = 2, H = 128, W = 128, h = 64, w = 64;
    const int MF = B * H * W;   // 32768
    const int MC = B * h * w;   // 8192

    char* ws = (char*)d_ws;
    size_t off = 0;
    auto alloc = [&](size_t bytes) {
        void* p = ws + off;
        off = (off + bytes + 255) & ~(size_t)255;
        return p;
    };
    unsigned short* f_emb    = (unsigned short*)alloc((size_t)MF * EMB * 2);
    unsigned short* c_emb    = (unsigned short*)alloc((size_t)MC * EMB * 2);
    float* f_conv            = (float*)alloc((size_t)MF * CST * 4);
    float* c_conv            = (float*)alloc((size_t)MC * CST * 4);
    unsigned short* wconT    = (unsigned short*)alloc(32 * 576 * 2);
    unsigned short* wcT      = (unsigned short*)alloc(128 * 128 * 2);
    unsigned short* wfT      = (unsigned short*)alloc(128 * 128 * 2);

    const int NEF = MF / 64;          // 512 fine embed blocks
    const int NEC = MC / 64;          // 128 coarse embed blocks
    const int NEB = NEF + NEC;        // 640 embed blocks
    const int NWT = 200;              // 51200 transpose elems / 256
    const int NCF = B * (H / 4) * (W / 32);   // 256 fine content blocks
    const int NCC = B * (h / 4) * (w / 32);   // 64 coarse content blocks

    embed_both_kernel<<<NEB + NWT, 256, 0, stream>>>(fine, w_sfine, coarse, w_scoarse, b_scoarse,
                                                     f_emb, c_emb, NEF, NEB,
                                                     w_content, w_coarse, w_fineout,
                                                     wconT, wcT, wfT);
    content_both_kernel<<<NCF + NCC, 256, 0, stream>>>(f_emb, c_emb, wconT, b_content,
                                                       f_conv, c_conv, NCF);
    carafe_final_kernel<<<B * 16 * 16, 256, 0, stream>>>(coarse, f_conv, c_conv, w_gate, b_gate,
                                                         wcT, wfT, b_coarse, b_fineout, out);
}

// Round 16
// 47.157 us; speedup vs baseline: 1.0363x; 1.0032x over previous
//
#include <hip/hip_runtime.h>
#include <hip/hip_bf16.h>
#include <cstdint>
#include <cstddef>

#define KSZ 5
#define KK 25
#define EMB 64
#define CC 128
#define FILTERS 128
#define CST 32   // padded conv-out stride (f_conv/c_conv rows, 128B aligned)

typedef __attribute__((ext_vector_type(8))) short short8;
typedef __attribute__((ext_vector_type(4))) float floatx4;

__device__ inline unsigned short f32_to_bf16(float f) {
    union { float f; unsigned u; } v; v.f = f;
    unsigned u = v.u;
    unsigned r = u + 0x7FFF + ((u >> 16) & 1);
    return (unsigned short)(r >> 16);
}

// ---------------- embed MFMA (M=64, X direct-from-global) + weight-transpose tails ----
#define XS_P 136
__global__ __launch_bounds__(256) void embed_both_kernel(
        const float* __restrict__ xf, const float* __restrict__ wsf,   // [128][64] f32
        const float* __restrict__ xc, const float* __restrict__ wsc,   // [128][64] f32
        const float* __restrict__ bias_c,
        unsigned short* __restrict__ yf, unsigned short* __restrict__ yc,
        int nf, int nemb,
        const float* __restrict__ w_content, const float* __restrict__ w_coarse,
        const float* __restrict__ w_fineout,
        unsigned short* __restrict__ wconT, unsigned short* __restrict__ wcT,
        unsigned short* __restrict__ wfT) {
    int tid = threadIdx.x;

    if ((int)blockIdx.x >= nemb) {
        int idx = (blockIdx.x - nemb) * 256 + tid;   // 0..51199
        if (idx < 18432) {
            int n = idx / 576, k = idx - n * 576;
            float v = (n < 25) ? w_content[k * 25 + n] : 0.0f;
            wconT[idx] = f32_to_bf16(v);
        } else if (idx < 34816) {
            int j = idx - 18432;
            int o = j >> 7, k = j & 127;
            wcT[j] = f32_to_bf16(w_coarse[k * 128 + o]);
        } else {
            int j = idx - 34816;
            int o = j >> 7, k = j & 127;
            wfT[j] = f32_to_bf16(w_fineout[k * 128 + o]);
        }
        return;
    }

    __shared__ unsigned short Ws[64 * XS_P];   // 17.4 KB
    bool is_f = (int)blockIdx.x < nf;
    int blk = is_f ? blockIdx.x : (blockIdx.x - nf);
    const float* x = is_f ? xf : xc;
    const float* wsrcf = is_f ? wsf : wsc;
    const float* bias = is_f ? nullptr : bias_c;
    unsigned short* y = is_f ? yf : yc;
    size_t row0 = (size_t)blk * 64;

    for (int ci = tid; ci < 2048; ci += 256) {
        int k = ci >> 4;
        int n4 = (ci & 15) * 4;
        float4 v = *(const float4*)(wsrcf + k * 64 + n4);
        Ws[(n4 + 0) * XS_P + k] = f32_to_bf16(v.x);
        Ws[(n4 + 1) * XS_P + k] = f32_to_bf16(v.y);
        Ws[(n4 + 2) * XS_P + k] = f32_to_bf16(v.z);
        Ws[(n4 + 3) * XS_P + k] = f32_to_bf16(v.w);
    }
    __syncthreads();

    int wid = tid >> 6, lane = tid & 63;
    int lr = lane & 15, hi = lane >> 4, lk = hi * 8;

    int arow = wid * 16 + lr;
    const float* xr = x + (row0 + arow) * 128;

    floatx4 acc[4];
    #pragma unroll
    for (int ni = 0; ni < 4; ++ni)
        acc[ni] = (floatx4){0.f, 0.f, 0.f, 0.f};

    #pragma unroll
    for (int kk = 0; kk < 4; ++kk) {
        float4 a0 = *(const float4*)(xr + kk * 32 + lk);
        float4 a1 = *(const float4*)(xr + kk * 32 + lk + 4);
        unsigned short ah[8];
        ah[0] = f32_to_bf16(a0.x); ah[1] = f32_to_bf16(a0.y);
        ah[2] = f32_to_bf16(a0.z); ah[3] = f32_to_bf16(a0.w);
        ah[4] = f32_to_bf16(a1.x); ah[5] = f32_to_bf16(a1.y);
        ah[6] = f32_to_bf16(a1.z); ah[7] = f32_to_bf16(a1.w);
        short8 a = *(const short8*)ah;
        #pragma unroll
        for (int ni = 0; ni < 4; ++ni) {
            short8 bb = *(const short8*)(&Ws[(ni * 16 + lr) * XS_P + kk * 32 + lk]);
            acc[ni] = __builtin_amdgcn_mfma_f32_16x16x32_bf16(a, bb, acc[ni], 0, 0, 0);
        }
    }

    #pragma unroll
    for (int ni = 0; ni < 4; ++ni) {
        int col = ni * 16 + lr;
        float bs = bias ? bias[col] : 0.0f;
        #pragma unroll
        for (int j = 0; j < 4; ++j) {
            int row = wid * 16 + hi * 4 + j;
            y[(row0 + row) * EMB + col] = f32_to_bf16(acc[ni][j] + bs);
        }
    }
}

// ---------------- content conv MFMA (both resolutions), pad-32 output ----------------
#define SP 72
#define SB 584
__global__ __launch_bounds__(256) void content_both_kernel(
        const unsigned short* __restrict__ embf,
        const unsigned short* __restrict__ embc,
        const unsigned short* __restrict__ wT,   // bf16 [32][576]
        const float* __restrict__ bias,          // [25]
        float* __restrict__ yf, float* __restrict__ yc,   // [*,CST] padded
        int nf) {
    __shared__ unsigned short Es[6 * 34 * SP];
    __shared__ unsigned short Bs[32 * SB];
    int tid = threadIdx.x;
    bool is_f = (int)blockIdx.x < nf;
    int blk = is_f ? blockIdx.x : (blockIdx.x - nf);
    const unsigned short* emb = is_f ? embf : embc;
    float* y = is_f ? yf : yc;
    int HT = is_f ? 32 : 16;
    int WT = is_f ? 4 : 2;
    int Hh = is_f ? 128 : 64;
    int Ww = is_f ? 128 : 64;

    int bx = blk % WT;
    int t = blk / WT;
    int by = t % HT;
    int b = t / HT;

    for (int ci = tid; ci < 1632; ci += 256) {
        int pi = ci >> 3, e8 = ci & 7;
        int hy = pi / 34, hx = pi - hy * 34;
        int gy = by * 4 + hy - 1, gx = bx * 32 + hx - 1;
        uint4 v = {0u, 0u, 0u, 0u};
        if (gy >= 0 && gy < Hh && gx >= 0 && gx < Ww)
            v = *(const uint4*)(emb + (((size_t)(b * Hh + gy)) * Ww + gx) * EMB + e8 * 8);
        *(uint4*)(&Es[pi * SP + e8 * 8]) = v;
    }
    for (int ci = tid; ci < 2304; ci += 256) {
        int n = ci / 72, k8 = ci - n * 72;
        *(uint4*)(&Bs[n * SB + k8 * 8]) = *(const uint4*)(wT + n * 576 + k8 * 8);
    }
    __syncthreads();

    int wid = tid >> 6, lane = tid & 63;
    int lr = lane & 15, hi = lane >> 4, lk = hi * 8;

    floatx4 acc[2][2];
    #pragma unroll
    for (int mi = 0; mi < 2; ++mi)
        #pragma unroll
        for (int ni = 0; ni < 2; ++ni)
            acc[mi][ni] = (floatx4){0.f, 0.f, 0.f, 0.f};

    #pragma unroll
    for (int tap = 0; tap < 9; ++tap) {
        int dy = tap / 3, dx = tap - dy * 3;
        #pragma unroll
        for (int ks = 0; ks < 2; ++ks) {
            short8 a[2], bb[2];
            #pragma unroll
            for (int mi = 0; mi < 2; ++mi) {
                int p = wid * 32 + mi * 16 + lr;
                int r = p >> 5, c = p & 31;
                a[mi] = *(const short8*)(&Es[((r + dy) * 34 + (c + dx)) * SP + ks * 32 + lk]);
            }
            #pragma unroll
            for (int ni = 0; ni < 2; ++ni)
                bb[ni] = *(const short8*)(&Bs[(ni * 16 + lr) * SB + tap * 64 + ks * 32 + lk]);
            #pragma unroll
            for (int mi = 0; mi < 2; ++mi)
                #pragma unroll
                for (int ni = 0; ni < 2; ++ni)
                    acc[mi][ni] = __builtin_amdgcn_mfma_f32_16x16x32_bf16(a[mi], bb[ni], acc[mi][ni], 0, 0, 0);
        }
    }

    #pragma unroll
    for (int mi = 0; mi < 2; ++mi) {
        #pragma unroll
        for (int ni = 0; ni < 2; ++ni) {
            int n = ni * 16 + lr;
            if (n < KK) {
                float bs = bias[n];
                #pragma unroll
                for (int j = 0; j < 4; ++j) {
                    int p = wid * 32 + mi * 16 + hi * 4 + j;
                    int r = p >> 5, c = p & 31;
                    size_t gq = ((size_t)(b * Hh + by * 4 + r)) * Ww + bx * 32 + c;
                    y[gq * CST + n] = acc[mi][ni][j] + bs;
                }
            }
        }
    }
}

// ================ fused carafe + gate + final double-GEMM + blend (M=64) ================
#define LDSP 136
__global__ __launch_bounds__(256) void carafe_final_kernel(
        const float* __restrict__ coarse,   // [B,64,64,128]
        const float* __restrict__ f_conv,   // [B,128,128,CST]
        const float* __restrict__ c_conv,   // [B,64,64,CST]
        const float* __restrict__ w_gate,   // [128]
        const float* __restrict__ b_gate,   // [1]
        const unsigned short* __restrict__ WcT,  // bf16 [o][k]
        const unsigned short* __restrict__ WfT,  // bf16 [p][o]
        const float* __restrict__ b_coarse,
        const float* __restrict__ b_fineout,
        float* __restrict__ out) {
    __shared__ __align__(16) char smem[58624];
    float* patches = (float*)smem;                        // [64][128]
    float* wsm     = (float*)(smem + 32768);              // [64][32]
    float* g_lds   = (float*)(smem + 40960);              // [16]
    unsigned short* Ws = (unsigned short*)smem;           // [128][LDSP] overlay
    unsigned short* Xs = (unsigned short*)(smem + 41216); // [64][LDSP]

    const int h = 64, w = 64, H2 = 128, W2 = 128;
    int tid = threadIdx.x;
    int blk = blockIdx.x;
    int cx0 = (blk & 15) * 4;
    int cy0 = ((blk >> 4) & 15) * 4;
    int b = blk >> 8;

    for (int ci = tid; ci < 2048; ci += 256) {
        int pi = ci >> 5;
        int c4 = (ci & 31) << 2;
        int sy = cy0 - 2 + (pi >> 3);
        int sx = cx0 - 2 + (pi & 7);
        float4 v = {0.f, 0.f, 0.f, 0.f};
        if (sy >= 0 && sy < h && sx >= 0 && sx < w)
            v = *(const float4*)(coarse + (((size_t)(b * h + sy)) * w + sx) * CC + c4);
        *(float4*)(&patches[pi * 128 + c4]) = v;
    }

    int wid = tid >> 6, lane = tid & 63;
    {
        int k = lane & 31;
        #pragma unroll
        for (int pass = 0; pass < 8; ++pass) {
            int fp = wid * 16 + pass * 2 + (lane >> 5);
            int fry = fp >> 3, frx = fp & 7;
            int fy = 2 * cy0 + fry, fx = 2 * cx0 + frx;
            int cy = cy0 + (fry >> 1), cx = cx0 + (frx >> 1);
            size_t fq = ((size_t)(b * H2 + fy)) * W2 + fx;
            size_t cq = ((size_t)(b * h + cy)) * w + cx;
            float v = -1e30f;
            if (k < KK)
                v = f_conv[fq * CST + k] + c_conv[cq * CST + k];
            float m = v;
            #pragma unroll
            for (int mask = 16; mask > 0; mask >>= 1)
                m = fmaxf(m, __shfl_xor(m, mask, 32));
            float e = (k < KK) ? __expf(v - m) : 0.0f;
            float s = e;
            #pragma unroll
            for (int mask = 16; mask > 0; mask >>= 1)
                s += __shfl_xor(s, mask, 32);
            wsm[fp * 32 + k] = e / s;    // rows 25..31 = exact 0.0
        }
    }
    __syncthreads();

    {
        int cp = tid >> 4;
        int part = tid & 15;
        int pidx = ((cp >> 2) + 2) * 8 + (cp & 3) + 2;
        const float* pc = patches + pidx * 128 + part * 8;
        float4 a0 = *(const float4*)(pc);
        float4 a1 = *(const float4*)(pc + 4);
        float4 g0 = *(const float4*)(w_gate + part * 8);
        float4 g1 = *(const float4*)(w_gate + part * 8 + 4);
        float acc = a0.x * g0.x + a0.y * g0.y + a0.z * g0.z + a0.w * g0.w
                  + a1.x * g1.x + a1.y * g1.y + a1.z * g1.z + a1.w * g1.w;
        #pragma unroll
        for (int mask = 8; mask > 0; mask >>= 1)
            acc += __shfl_xor(acc, mask, 16);
        if (part == 0) {
            float z = acc + b_gate[0];
            g_lds[cp] = 1.0f / (1.0f + __expf(-z));
        }
    }

    // ---- FAITHFUL gather, 4 fine px per thread per coarse pixel ----
    {
        int c   = tid & 127;
        int cpg = tid >> 7;
        int offs[28];
        int c25 = c * 25;
        #pragma unroll
        for (int j = 0; j < 28; ++j) {
            int i = c25 + j;
            int p = i >> 7;
            int ch = i & 127;
            int pd = (p * 205) >> 10;   // p/5
            int pm = p - pd * 5;
            offs[j] = (pd * 8 + pm) * 128 + ch;
        }
        #pragma unroll
        for (int it = 0; it < 8; ++it) {
            int cp = cpg * 8 + it;
            int ry = cp >> 2, rx = cp & 3;
            int cpbase = (ry * 8 + rx) * 128;
            int fpA = (2 * ry) * 8 + 2 * rx;   // 4 fine px: fpA, fpA+1, fpA+8, fpA+9
            float a00 = 0.f, a01 = 0.f, a10 = 0.f, a11 = 0.f;
            #pragma unroll
            for (int j4 = 0; j4 < 7; ++j4) {
                float4 wA = *(const float4*)(&wsm[fpA * 32 + j4 * 4]);
                float4 wB = *(const float4*)(&wsm[(fpA + 1) * 32 + j4 * 4]);
                float4 wC = *(const float4*)(&wsm[(fpA + 8) * 32 + j4 * 4]);
                float4 wD = *(const float4*)(&wsm[(fpA + 9) * 32 + j4 * 4]);
                #pragma unroll
                for (int jj = 0; jj < 4; ++jj) {
                    float pv = patches[cpbase + offs[j4 * 4 + jj]];
                    float wa = (jj == 0) ? wA.x : (jj == 1) ? wA.y : (jj == 2) ? wA.z : wA.w;
                    float wb = (jj == 0) ? wB.x : (jj == 1) ? wB.y : (jj == 2) ? wB.z : wB.w;
                    float wc = (jj == 0) ? wC.x : (jj == 1) ? wC.y : (jj == 2) ? wC.z : wC.w;
                    float wd = (jj == 0) ? wD.x : (jj == 1) ? wD.y : (jj == 2) ? wD.z : wD.w;
                    a00 += wa * pv;
                    a01 += wb * pv;
                    a10 += wc * pv;
                    a11 += wd * pv;
                }
            }
            Xs[fpA * LDSP + c]       = f32_to_bf16(a00);
            Xs[(fpA + 1) * LDSP + c] = f32_to_bf16(a01);
            Xs[(fpA + 8) * LDSP + c] = f32_to_bf16(a10);
            Xs[(fpA + 9) * LDSP + c] = f32_to_bf16(a11);
        }
    }
    __syncthreads();

    {
        const uint4* wsrc = (const uint4*)WcT;
        for (int ci = tid; ci < 2048; ci += 256) {
            int r = ci >> 4, c = ci & 15;
            *(uint4*)(&Ws[r * LDSP + c * 8]) = wsrc[ci];
        }
    }
    __syncthreads();

    int wm = wid >> 1, wn = wid & 1;
    int lr = lane & 15;
    int lk = (lane >> 4) * 8;
    int lrow4 = (lane >> 4) * 4;

    floatx4 acc1[2][4];
    #pragma unroll
    for (int mi = 0; mi < 2; ++mi)
        #pragma unroll
        for (int ni = 0; ni < 4; ++ni)
            acc1[mi][ni] = (floatx4){0.f, 0.f, 0.f, 0.f};

    #pragma unroll
    for (int kk = 0; kk < 128; kk += 32) {
        short8 a[2], bb[4];
        #pragma unroll
        for (int mi = 0; mi < 2; ++mi)
            a[mi] = *(const short8*)(&Xs[(wm * 32 + mi * 16 + lr) * LDSP + kk + lk]);
        #pragma unroll
        for (int ni = 0; ni < 4; ++ni)
            bb[ni] = *(const short8*)(&Ws[(wn * 64 + ni * 16 + lr) * LDSP + kk + lk]);
        #pragma unroll
        for (int mi = 0; mi < 2; ++mi)
            #pragma unroll
            for (int ni = 0; ni < 4; ++ni)
                acc1[mi][ni] = __builtin_amdgcn_mfma_f32_16x16x32_bf16(a[mi], bb[ni], acc1[mi][ni], 0, 0, 0);
    }
    __syncthreads();

    {
        const uint4* wsrc = (const uint4*)WfT;
        for (int ci = tid; ci < 2048; ci += 256) {
            int r = ci >> 4, c = ci & 15;
            *(uint4*)(&Ws[r * LDSP + c * 8]) = wsrc[ci];
        }
    }
    #pragma unroll
    for (int mi = 0; mi < 2; ++mi) {
        #pragma unroll
        for (int ni = 0; ni < 4; ++ni) {
            int col = wn * 64 + ni * 16 + lr;
            float bc = b_coarse[col];
            #pragma unroll
            for (int j = 0; j < 4; ++j) {
                int row = wm * 32 + mi * 16 + lrow4 + j;
                float v = acc1[mi][ni][j] + bc;
                acc1[mi][ni][j] = v;
                Xs[row * LDSP + col] = f32_to_bf16(v);
            }
        }
    }
    __syncthreads();

    floatx4 acc2[2][4];
    #pragma unroll
    for (int mi = 0; mi < 2; ++mi)
        #pragma unroll
        for (int ni = 0; ni < 4; ++ni)
            acc2[mi][ni] = (floatx4){0.f, 0.f, 0.f, 0.f};

    #pragma unroll
    for (int kk = 0; kk < 128; kk += 32) {
        short8 a[2], bb[4];
        #pragma unroll
        for (int mi = 0; mi < 2; ++mi)
            a[mi] = *(const short8*)(&Xs[(wm * 32 + mi * 16 + lr) * LDSP + kk + lk]);
        #pragma unroll
        for (int ni = 0; ni < 4; ++ni)
            bb[ni] = *(const short8*)(&Ws[(wn * 64 + ni * 16 + lr) * LDSP + kk + lk]);
        #pragma unroll
        for (int mi = 0; mi < 2; ++mi)
            #pragma unroll
            for (int ni = 0; ni < 4; ++ni)
                acc2[mi][ni] = __builtin_amdgcn_mfma_f32_16x16x32_bf16(a[mi], bb[ni], acc2[mi][ni], 0, 0, 0);
    }

    #pragma unroll
    for (int mi = 0; mi < 2; ++mi) {
        #pragma unroll
        for (int ni = 0; ni < 4; ++ni) {
            int col = wn * 64 + ni * 16 + lr;
            float bf = b_fineout[col];
            #pragma unroll
            for (int j = 0; j < 4; ++j) {
                int row = wm * 32 + mi * 16 + lrow4 + j;
                int fry = row >> 3, frx = row & 7;
                float g = g_lds[((fry >> 1) << 2) + (frx >> 1)];
                int fy = 2 * cy0 + fry, fx = 2 * cx0 + frx;
                size_t q = ((size_t)(b * H2 + fy)) * W2 + fx;
                float co = acc1[mi][ni][j];
                float fo = acc2[mi][ni][j] + bf;
                out[q * FILTERS + col] = g * fo + (1.0f - g) * co;
            }
        }
    }
}

extern "C" void kernel_launch(void* const* d_in, const int* in_sizes, int n_in,
                              void* d_out, int out_size, void* d_ws, size_t ws_size,
                              hipStream_t stream) {
    const float* fine      = (const float*)d_in[0];
    const float* coarse    = (const float*)d_in[1];
    const float* w_gate    = (const float*)d_in[2];
    const float* b_gate    = (const float*)d_in[3];
    const float* w_sfine   = (const float*)d_in[4];
    const float* w_scoarse = (const float*)d_in[5];
    const float* b_scoarse = (const float*)d_in[6];
    const float* w_content = (const float*)d_in[7];
    const float* b_content = (const float*)d_in[8];
    const float* w_coarse  = (const float*)d_in[9];
    const float* b_coarse  = (const float*)d_in[10];
    const float* w_fineout = (const float*)d_in[11];
    const float* b_fineout = (const float*)d_in[12];
    float* out = (float*)d_out;

    const int B = 2, H = 128, W = 128, h = 64, w = 64;
    const int MF = B * H * W;   // 32768
    const int MC = B * h * w;   // 8192

    char* ws = (char*)d_ws;
    size_t off = 0;
    auto alloc = [&](size_t bytes) {
        void* p = ws + off;
        off = (off + bytes + 255) & ~(size_t)255;
        return p;
    };
    unsigned short* f_emb    = (unsigned short*)alloc((size_t)MF * EMB * 2);
    unsigned short* c_emb    = (unsigned short*)alloc((size_t)MC * EMB * 2);
    float* f_conv            = (float*)alloc((size_t)MF * CST * 4);
    float* c_conv            = (float*)alloc((size_t)MC * CST * 4);
    unsigned short* wconT    = (unsigned short*)alloc(32 * 576 * 2);
    unsigned short* wcT      = (unsigned short*)alloc(128 * 128 * 2);
    unsigned short* wfT      = (unsigned short*)alloc(128 * 128 * 2);

    const int NEF = MF / 64;          // 512 fine embed blocks
    const int NEC = MC / 64;          // 128 coarse embed blocks
    const int NEB = NEF + NEC;        // 640 embed blocks
    const int NWT = 200;              // 51200 transpose elems / 256
    const int NCF = B * (H / 4) * (W / 32);   // 256 fine content blocks
    const int NCC = B * (h / 4) * (w / 32);   // 64 coarse content blocks

    embed_both_kernel<<<NEB + NWT, 256, 0, stream>>>(fine, w_sfine, coarse, w_scoarse, b_scoarse,
                                                     f_emb, c_emb, NEF, NEB,
                                                     w_content, w_coarse, w_fineout,
                                                     wconT, wcT, wfT);
    content_both_kernel<<<NCF + NCC, 256, 0, stream>>>(f_emb, c_emb, wconT, b_content,
                                                       f_conv, c_conv, NCF);
    carafe_final_kernel<<<B * 16 * 16, 256, 0, stream>>>(coarse, f_conv, c_conv, w_gate, b_gate,
                                                         wcT, wfT, b_coarse, b_fineout, out);
}